// Round 10
// baseline (285.948 us; speedup 1.0000x reference)
//
#include <hip/hip_runtime.h>

#define NPG    50
#define HF     128
#define FDIM   64
#define NGRAPH 2048
#define EPG    400
#define SP     72     // featT row stride (bf16), 16B-aligned rows, bank-skewed
#define HB     136    // hbuf row stride (bf16), 16B-aligned rows
#define CNTW   16     // cnt row stride in ints (64 byte-counts per row)

typedef __attribute__((ext_vector_type(8))) short bf16x8;
typedef __attribute__((ext_vector_type(4))) float floatx4;
typedef __bf16 bfv2 __attribute__((ext_vector_type(2)));

__device__ __forceinline__ float leaky(float x, float s) { return x >= 0.f ? x : x * s; }

__device__ __forceinline__ unsigned short f2bf(float f) {
    __bf16 b = (__bf16)f;
    unsigned short u;
    __builtin_memcpy(&u, &b, 2);
    return u;
}
__device__ __forceinline__ unsigned f2bfpk(float a, float b) {
    bfv2 v;
    v[0] = (__bf16)a;
    v[1] = (__bf16)b;
    unsigned u;
    __builtin_memcpy(&u, &v, 4);
    return u;
}
__device__ __forceinline__ float bf2f(unsigned short h) {
    return __uint_as_float(((unsigned)h) << 16);
}
__device__ __forceinline__ int fkey(float f) { int b = __float_as_int(f); return b >= 0 ? b : b ^ 0x7fffffff; }
__device__ __forceinline__ float funkey(int k) { return __int_as_float(k >= 0 ? k : k ^ 0x7fffffff); }

// ---- AGPR parking (R10) ----------------------------------------------------
// Six rounds (R2/R4/R6/R7/R8/R9) spilled at the (512,8) 64-reg budget with
// arch-VGPR pinned at 32: the MFMA A-operands (afr, ap) were held on the ARCH
// side while the acc side had headroom.  gfx950 MFMA reads A/B from VGPR OR
// AGPR (cdna4_isa §10); an empty asm with "+a" forces the value's home into
// the accumulator file.  GEMM: afr(16a)+acc(16a)=32a; agg: ap(8a)+ag(16a)=24a;
// arch side drops to ~28-32 -> fits the 32-reg arch budget without spill.
__device__ __forceinline__ bf16x8 park_a(bf16x8 x) {
    floatx4 v;
    __builtin_memcpy(&v, &x, 16);
    asm volatile("" : "+a"(v));
    __builtin_memcpy(&x, &v, 16);
    return x;
}

// ---- DPP cross-lane (VALU pipe, zero LDS) ----
template <int CTRL>
__device__ __forceinline__ float dpp_addx(float x) {
    int yi = __builtin_amdgcn_update_dpp(0, __float_as_int(x), CTRL, 0xf, 0xf, true);
    return x + __int_as_float(yi);
}
__device__ __forceinline__ float row16_sum(float x) {
    x = dpp_addx<0xB1>(x);    // quad_perm(1,0,3,2)
    x = dpp_addx<0x4E>(x);    // quad_perm(2,3,0,1)
    x = dpp_addx<0x141>(x);   // row_half_mirror
    x = dpp_addx<0x140>(x);   // row_mirror
    return x;
}

// sigma column permutation for hbuf storage (within each 64-col head):
//   store position p = (c&15)*4 + ((c>>4)&3);  inverse c = (p&3)*16 + (p>>2)
// Epilogue's per-thread cols {nt*16+l16} are CONTIGUOUS in LDS.
// wt1/wt2 k-rows permuted identically in prep_w; layer-0 k (x feats) unpermuted.

__global__ void prep_w(const float* __restrict__ W0, const float* __restrict__ rW0,
                       const float* __restrict__ W1, const float* __restrict__ W2,
                       const float* __restrict__ al0, const float* __restrict__ ar0,
                       const float* __restrict__ al1, const float* __restrict__ ar1,
                       const float* __restrict__ al2, const float* __restrict__ ar2,
                       unsigned short* __restrict__ wt0, unsigned short* __restrict__ wt1,
                       unsigned short* __restrict__ wt2) {
    if (blockIdx.x >= 64) {
        int gid = (blockIdx.x - 64) * 256 + threadIdx.x;   // [0, 5120)
        if (gid < 1024) {            // layer 0 attn tile: k = true x-features
            int la = gid >> 6, k = gid & 63;
            unsigned short o = 0;
            if (la < 8) {
                const float* a = (la < 4) ? al0 : ar0;
                int h = (la >> 1) & 1;
                float v = 0.f;
                for (int f = 0; f < 64; ++f) v += W0[k * 128 + h * 64 + f] * a[h * 64 + f];
                __bf16 hi = (__bf16)v;
                if (la & 1) o = f2bf(v - (float)hi);
                else __builtin_memcpy(&o, &hi, 2);
            }
            wt0[(256 + la) * 64 + k] = o;
        } else {                     // layers 1/2 attn tiles: k sigma-permuted
            int q = gid - 1024;
            int l = q >> 11;
            int la = (q >> 7) & 15, kp = q & 127;
            int ktrue = (kp & 64) + ((kp & 3) * 16) + ((kp & 63) >> 2);
            const float* W = l ? W2 : W1;
            unsigned short o = 0;
            if (la < 8) {
                const float* a = l ? ((la < 4) ? al2 : ar2) : ((la < 4) ? al1 : ar1);
                int h = (la >> 1) & 1;
                float v = 0.f;
                for (int f = 0; f < 64; ++f) v += W[ktrue * 128 + h * 64 + f] * a[h * 64 + f];
                __bf16 hi = (__bf16)v;
                if (la & 1) o = f2bf(v - (float)hi);
                else __builtin_memcpy(&o, &hi, 2);
            }
            (l ? wt2 : wt1)[(128 + la) * 128 + kp] = o;
        }
        return;
    }
    int i = blockIdx.x * 256 + threadIdx.x;
    if (i < 256 * 64) {              // wt0 main: k = true x-features
        int n = i >> 6, k = i & 63;
        float v = (n < 128) ? W0[k * 128 + n] : rW0[k * 128 + (n - 128)];
        wt0[i] = f2bf(v);
    }
    if (i < 128 * 128) {             // wt1/wt2 main: k sigma-permuted
        int n = i >> 7, kp = i & 127;
        int ktrue = (kp & 64) + ((kp & 3) * 16) + ((kp & 63) >> 2);
        wt1[i] = f2bf(W1[ktrue * 128 + n]);
        wt2[i] = f2bf(W2[ktrue * 128 + n]);
    }
}

// One GAT layer, fully in-block.  hbuf (sigma-ordered cols) holds
// (RESW: x@resW0, else: input h) on entry to the epilogue, this layer's y on
// exit.  NO float atomics: uniquely-owned LDS slots + fixed-order sums ->
// bit-deterministic.  R10 = R6 structure + sched_barrier per N-tile (R9) +
// AGPR parking of afr/ap (see park_a).  Math order unchanged -> bit-identical.
template <int K, bool RESW>
__device__ __forceinline__ void gat_layer(
    const float* __restrict__ xrow,             // RESW: this graph's x base
    const unsigned short* __restrict__ Wt,
    const float* __restrict__ gp, const float* __restrict__ bp,
    float* __restrict__ out, int layer, int g, int t,
    unsigned short* featT, unsigned short* hbuf, int* cnt,
    float* el_s, float* er_s, int* elmax_i,
    float* lnp, float* lnq, float* psum4, float* gbL)
{
    const int w = t >> 6, lane = t & 63, quad = lane >> 4, l16 = lane & 15;
    constexpr int KS = K / 32;
    constexpr int ATTN_ROW = RESW ? 256 : 128;  // attn tile base row in Wt
    const int mt = w & 3;
    int mrow = mt * 16 + l16;
    if (mrow >= NPG) mrow = NPG - 1;
    const floatx4 zf = {0.f, 0.f, 0.f, 0.f};

    // per-layer g|b reload, sigma-order.  Written before B1, read after B2.
    if (t < HF) {
        int p = (t & 64) + ((t & 15) * 4) + ((t >> 4) & 3);
        gbL[p] = gp[t];
        gbL[HF + p] = bp[t];
    }

    // ---- A-fragments: loaded here, PARKED IN AGPRs ----
    bf16x8 afr[KS];
    if constexpr (RESW) {
        const float* hrow = xrow + (size_t)mrow * 64;
#pragma unroll
        for (int ks = 0; ks < KS; ++ks) {
            int k0 = ks * 32 + quad * 8;
            float4 p0 = *(const float4*)(hrow + k0);
            float4 p1 = *(const float4*)(hrow + k0 + 4);
            unsigned au[4] = {f2bfpk(p0.x, p0.y), f2bfpk(p0.z, p0.w),
                              f2bfpk(p1.x, p1.y), f2bfpk(p1.z, p1.w)};
            __builtin_memcpy(&afr[ks], au, 16);
            afr[ks] = park_a(afr[ks]);
        }
    } else {
#pragma unroll
        for (int ks = 0; ks < KS; ++ks) {
            afr[ks] = *(const bf16x8*)&hbuf[mrow * HB + ks * 32 + quad * 8];
            afr[ks] = park_a(afr[ks]);
        }
    }

    // ---- main GEMM via MFMA + featT/res stores ----
    if constexpr (RESW) {
        // two SEQUENTIAL passes of 4 N-tiles: peak acc = 16 AGPRs.
        // unroll 1 is load-bearing -- full unroll re-fuses to 32 AGPRs.
#pragma unroll 1
        for (int half = 0; half < 2; ++half) {
            const int nb = (w >> 2) * 8 + half * 4;
            floatx4 acc[4];
#pragma unroll
            for (int nt = 0; nt < 4; ++nt) acc[nt] = zf;
#pragma unroll
            for (int nt = 0; nt < 4; ++nt) {
                const unsigned short* wrow = Wt + (size_t)((nb + nt) * 16 + l16) * K;
#pragma unroll
                for (int ks = 0; ks < KS; ++ks) {
                    bf16x8 b = *(const bf16x8*)(wrow + ks * 32 + quad * 8);
                    acc[nt] = __builtin_amdgcn_mfma_f32_16x16x32_bf16(afr[ks], b, acc[nt], 0, 0, 0);
                }
                __builtin_amdgcn_sched_barrier(0);   // cap B-load hoist: 1 N-tile
            }
#pragma unroll
            for (int nt = 0; nt < 4; ++nt) {
                int n = (nb + nt) * 16 + l16;
                if (n < HF) {
                    uint2 pk = {f2bfpk(acc[nt][0], acc[nt][1]),
                                f2bfpk(acc[nt][2], acc[nt][3])};
                    *(uint2*)&featT[n * SP + mt * 16 + quad * 4] = pk;
                } else {
                    int c = n - HF;                       // residual -> sigma pos
                    int spos = (c & 64) + ((c & 15) * 4) + ((c >> 4) & 3);
#pragma unroll
                    for (int r = 0; r < 4; ++r) {
                        int dr = mt * 16 + quad * 4 + r;
                        if (dr < NPG) hbuf[dr * HB + spos] = f2bf(acc[nt][r]);
                    }
                }
            }
        }
    } else {
        const int ntbase = (w >> 2) * 4;
        floatx4 acc[4];
#pragma unroll
        for (int nt = 0; nt < 4; ++nt) acc[nt] = zf;
#pragma unroll
        for (int nt = 0; nt < 4; ++nt) {
            const unsigned short* wrow = Wt + (size_t)((ntbase + nt) * 16 + l16) * K;
#pragma unroll
            for (int ks = 0; ks < KS; ++ks) {
                bf16x8 b = *(const bf16x8*)(wrow + ks * 32 + quad * 8);
                acc[nt] = __builtin_amdgcn_mfma_f32_16x16x32_bf16(afr[ks], b, acc[nt], 0, 0, 0);
            }
            __builtin_amdgcn_sched_barrier(0);       // cap B-load hoist: 1 N-tile
        }
#pragma unroll
        for (int nt = 0; nt < 4; ++nt) {
            int n = (ntbase + nt) * 16 + l16;
            uint2 pk = {f2bfpk(acc[nt][0], acc[nt][1]),
                        f2bfpk(acc[nt][2], acc[nt][3])};
            *(uint2*)&featT[n * SP + mt * 16 + quad * 4] = pk;
        }
    }

    // ---- el/er via the appended attn N-tile; hi+lo merged with DPP xor1 ----
    if (w < 4) {
        floatx4 ae = zf;
        const unsigned short* wrow = Wt + (size_t)(ATTN_ROW + l16) * K;
#pragma unroll
        for (int ks = 0; ks < KS; ++ks) {
            bf16x8 b = *(const bf16x8*)(wrow + ks * 32 + quad * 8);
            ae = __builtin_amdgcn_mfma_f32_16x16x32_bf16(afr[ks], b, ae, 0, 0, 0);
        }
#pragma unroll
        for (int r = 0; r < 4; ++r) {
            float v = dpp_addx<0xB1>(ae[r]);              // hi + lo (xor1, VALU)
            if ((l16 & 1) == 0 && l16 < 8) {
                int row = mt * 16 + quad * 4 + r;
                int hd2 = (l16 >> 1) & 1;
                if (l16 < 4) {
                    el_s[hd2 * 64 + row] = v;
                    atomicMax(&elmax_i[hd2], fkey(v));    // int max: exact
                } else {
                    er_s[hd2 * 64 + row] = v;
                }
            }
        }
    }
    __syncthreads();   // B1

    // ---- exp A-frag + aggregation MFMA + epilogue ----
    const int hd = w >> 2, amt = w & 3;
    const int d = amt * 16 + l16;    // A-frag dst row

    const float erd = er_s[hd * 64 + d];
    const float md = leaky(funkey(elmax_i[hd]) + erd, 0.2f);
    const int dcl = d < NPG ? d : NPG - 1;
    const int* crow = &cnt[dcl * CNTW];

    bf16x8 ap[2];
    float rowsum = 0.f;
#pragma unroll
    for (int ks = 0; ks < 2; ++ks) {
        float4 ev0 = *(const float4*)&el_s[hd * 64 + ks * 32 + quad * 8];
        float4 ev1 = *(const float4*)&el_s[hd * 64 + ks * 32 + quad * 8 + 4];
        const float ev[8] = {ev0.x, ev0.y, ev0.z, ev0.w, ev1.x, ev1.y, ev1.z, ev1.w};
        int2 cw = *(const int2*)&crow[ks * 8 + quad * 2];   // 8 byte-counts
        unsigned au[4];
#pragma unroll
        for (int jp = 0; jp < 4; ++jp) {
            float e0 = ev[2 * jp] + erd;
            float e1 = ev[2 * jp + 1] + erd;
            e0 = fmaxf(e0, 0.2f * e0);
            e1 = fmaxf(e1, 0.2f * e1);
            float p0 = __expf(e0 - md);
            float p1 = __expf(e1 - md);
            int w32 = (jp & 2) ? cw.y : cw.x;
            int sh = (jp & 1) * 16;
            int c0 = (w32 >> sh) & 0xff;
            int c1 = (w32 >> (sh + 8)) & 0xff;
            unsigned pk = f2bfpk((float)c0 * p0, (float)c1 * p1);  // c==0 -> exact 0
            au[jp] = pk;
            rowsum += __uint_as_float(pk << 16) + __uint_as_float(pk & 0xffff0000u);
        }
        __builtin_memcpy(&ap[ks], au, 16);
        ap[ks] = park_a(ap[ks]);     // A-operand of the agg MFMA -> AGPR home
    }
    rowsum += __shfl_xor(rowsum, 16, 64);
    rowsum += __shfl_xor(rowsum, 32, 64);
    const float rden = 1.f / fmaxf(rowsum, 1e-30f);

    floatx4 ag[4];
#pragma unroll
    for (int nt = 0; nt < 4; ++nt) ag[nt] = zf;
#pragma unroll
    for (int nt = 0; nt < 4; ++nt) {
        const unsigned short* fr = &featT[(hd * 64 + nt * 16 + l16) * SP];
#pragma unroll
        for (int ks = 0; ks < 2; ++ks) {
            bf16x8 b = *(const bf16x8*)(fr + ks * 32 + quad * 8);
            ag[nt] = __builtin_amdgcn_mfma_f32_16x16x32_bf16(ap[ks], b, ag[nt], 0, 0, 0);
        }
    }

    // scale + residual (sigma-packed b64 read); LN partials via DPP row-sum.
    // rden for row quad*4+r shuffled INLINE (no hoisted array).
    float s1[4] = {0, 0, 0, 0}, s2[4] = {0, 0, 0, 0};
#pragma unroll
    for (int r = 0; r < 4; ++r) {
        int dd = amt * 16 + quad * 4 + r;
        int dc = dd < NPG ? dd : NPG - 1;
        float rdv = __shfl(rden, quad * 4 + r, 16);
        uint2 rv = *(const uint2*)&hbuf[dc * HB + hd * 64 + l16 * 4];
#pragma unroll
        for (int nt = 0; nt < 4; ++nt) {
            unsigned hw = (nt & 1) ? ((nt & 2) ? rv.y >> 16 : rv.x >> 16)
                                   : ((nt & 2) ? rv.y & 0xffffu : rv.x & 0xffffu);
            float vv = fmaf(ag[nt][r], rdv, bf2f((unsigned short)hw));
            ag[nt][r] = vv;
            s1[r] += vv;
            s2[r] = fmaf(vv, vv, s2[r]);
        }
    }
#pragma unroll
    for (int r = 0; r < 4; ++r) {
        s1[r] = row16_sum(s1[r]);     // DPP: VALU pipe, zero LDS
        s2[r] = row16_sum(s2[r]);
    }
    if (l16 == 0) {
#pragma unroll
        for (int r = 0; r < 4; ++r) {
            int dd = amt * 16 + quad * 4 + r;   // slot [hd][dd]: single writer
            lnp[hd * 64 + dd] = s1[r];
            lnq[hd * 64 + dd] = s2[r];
        }
    }
    __syncthreads();   // B2: LN slots written; hbuf/featT reads done

    // re-arm elmax for the next layer (reads finished at B2, writes after B3)
    if (t < 2) elmax_i[t] = (int)0x80000000;

    // epilogue: scalar lnp/lnq reads per row; g/b as one float4 pair
    float4 ga = *(const float4*)&gbL[hd * 64 + l16 * 4];
    float4 ba = *(const float4*)&gbL[HF + hd * 64 + l16 * 4];

    float part[4] = {0, 0, 0, 0};
#pragma unroll
    for (int r = 0; r < 4; ++r) {
        int dd = amt * 16 + quad * 4 + r;
        if (dd < NPG) {
            float mu = (lnp[dd] + lnp[64 + dd]) * (1.f / HF);   // head0 + head1
            float rs = rsqrtf((lnq[dd] + lnq[64 + dd]) * (1.f / HF) - mu * mu + 1e-5f);
            float y4[4];
#pragma unroll
            for (int nt = 0; nt < 4; ++nt) {
                float y = (ag[nt][r] - mu) * rs * ga[nt] + ba[nt];
                y = leaky(y, 0.1f);
                y4[nt] = y;
                part[nt] += y;
            }
            uint2 pk = {f2bfpk(y4[0], y4[1]), f2bfpk(y4[2], y4[3])};
            *(uint2*)&hbuf[dd * HB + hd * 64 + l16 * 4] = pk;   // sigma-packed
        }
    }
#pragma unroll
    for (int nt = 0; nt < 4; ++nt) {
        part[nt] += __shfl_xor(part[nt], 16, 64);
        part[nt] += __shfl_xor(part[nt], 32, 64);
    }
    if (quad == 0) {
#pragma unroll
        for (int nt = 0; nt < 4; ++nt)
            psum4[amt * HF + hd * 64 + nt * 16 + l16] = part[nt];  // TRUE col idx
    }
    __syncthreads();   // B3: y visible (next layer A-frags), psum4 complete

    if (t < FDIM) {
        float s = 0.f;
#pragma unroll
        for (int a4 = 0; a4 < 4; ++a4)                   // fixed summation order
            s += psum4[a4 * HF + t] + psum4[a4 * HF + t + FDIM];
        out[(size_t)g * (3 * FDIM) + layer * FDIM + t] = leaky(s * (1.f / (2 * NPG)), 0.1f);
    }
}

// One block per graph runs all 3 layers.  (512,8): 4 blocks/CU.  R10 moves
// the MFMA A-operands (afr, ap) into the AGPR half of the unified file --
// the diagnosed reason arch-VGPR was pinned at 32 with ~18 dwords spilled.
// Spill tripwire: WRITE_SIZE >= 50 MB => 64-reg infeasible, revert to R6.
__global__ __launch_bounds__(512, 8) void gat3_kernel(
    const float* __restrict__ x,
    const unsigned short* __restrict__ wt0,
    const unsigned short* __restrict__ wt1,
    const unsigned short* __restrict__ wt2,
    const float* __restrict__ g0, const float* __restrict__ b0,
    const float* __restrict__ g1, const float* __restrict__ b1,
    const float* __restrict__ g2, const float* __restrict__ b2,
    const int* __restrict__ src, const int* __restrict__ dst,
    float* __restrict__ out)
{
    __shared__ unsigned short featT[HF * SP];   // 18432 B
    __shared__ unsigned short hbuf[NPG * HB];   // 13600 B (res/h/y, sigma cols)
    __shared__ int cnt[NPG * CNTW];             // 3200 B, byte counts
    __shared__ float el_s[128], er_s[128];
    __shared__ int elmax_i[2];
    __shared__ float lnp[128], lnq[128];        // LN partials [head][row]
    __shared__ float psum4[4 * HF];             // readout partials [amt][col]
    __shared__ float gbL[2 * HF];               // current layer's [g|b], sigma

    const int g = blockIdx.x, t = threadIdx.x;
    const int nbase = g * NPG;

    // independent global loads at cycle 0
    int es = 0, ed = 0;
    if (t < EPG) { es = src[g * EPG + t] - nbase; ed = dst[g * EPG + t] - nbase; }

    // init
    for (int i = t; i < NPG * CNTW; i += 512) cnt[i] = 0;
    if (t < 2) elmax_i[t] = (int)0x80000000;
    __syncthreads();

    // edge counts (byte-packed, 4/int), once for all 3 layers.
    if (t < EPG) atomicAdd(&cnt[ed * CNTW + (es >> 2)], 1 << ((es & 3) * 8));
    if (t < NPG) atomicAdd(&cnt[t * CNTW + (t >> 2)], 1 << ((t & 3) * 8));

    const float* xrow = x + (size_t)nbase * 64;
    gat_layer<64, true>(xrow, wt0, g0, b0, out, 0, g, t,
                        featT, hbuf, cnt, el_s, er_s, elmax_i, lnp, lnq, psum4, gbL);
    gat_layer<128, false>(nullptr, wt1, g1, b1, out, 1, g, t,
                          featT, hbuf, cnt, el_s, er_s, elmax_i, lnp, lnq, psum4, gbL);
    gat_layer<128, false>(nullptr, wt2, g2, b2, out, 2, g, t,
                          featT, hbuf, cnt, el_s, er_s, elmax_i, lnp, lnq, psum4, gbL);
}

extern "C" void kernel_launch(void* const* d_in, const int* in_sizes, int n_in,
                              void* d_out, int out_size, void* d_ws, size_t ws_size,
                              hipStream_t stream) {
    const float* x   = (const float*)d_in[0];
    const float* W0  = (const float*)d_in[1];
    const float* al0 = (const float*)d_in[2];
    const float* ar0 = (const float*)d_in[3];
    const float* rW0 = (const float*)d_in[4];
    const float* g0  = (const float*)d_in[5];
    const float* b0  = (const float*)d_in[6];
    const float* W1  = (const float*)d_in[7];
    const float* al1 = (const float*)d_in[8];
    const float* ar1 = (const float*)d_in[9];
    const float* g1  = (const float*)d_in[10];
    const float* b1  = (const float*)d_in[11];
    const float* W2  = (const float*)d_in[12];
    const float* al2 = (const float*)d_in[13];
    const float* ar2 = (const float*)d_in[14];
    const float* g2  = (const float*)d_in[15];
    const float* b2  = (const float*)d_in[16];
    const int* src   = (const int*)d_in[17];
    const int* dst   = (const int*)d_in[18];
    float* out = (float*)d_out;

    unsigned short* wt0 = (unsigned short*)d_ws;            // 272 x 64
    unsigned short* wt1 = wt0 + 272 * 64;                   // 144 x 128
    unsigned short* wt2 = wt1 + 144 * 128;                  // 144 x 128

    prep_w<<<84, 256, 0, stream>>>(W0, rW0, W1, W2, al0, ar0, al1, ar1, al2, ar2,
                                   wt0, wt1, wt2);
    gat3_kernel<<<NGRAPH, 512, 0, stream>>>(
        x, wt0, wt1, wt2, g0, b0, g1, b1, g2, b2, src, dst, out);
}

// Round 11
// 228.439 us; speedup vs baseline: 1.2518x; 1.2518x over previous
//
#include <hip/hip_runtime.h>

#define NPG    50
#define HF     128
#define FDIM   64
#define NGRAPH 2048
#define EPG    400
#define SP     72     // featT row stride (bf16), 16B-aligned rows, bank-skewed
#define HB     136    // hbuf row stride (bf16), 16B-aligned rows
#define CNTW   16     // cnt row stride in ints (64 byte-counts per row)

typedef __attribute__((ext_vector_type(8))) short bf16x8;
typedef __attribute__((ext_vector_type(4))) float floatx4;
typedef __bf16 bfv2 __attribute__((ext_vector_type(2)));

__device__ __forceinline__ float leaky(float x, float s) { return x >= 0.f ? x : x * s; }

__device__ __forceinline__ unsigned short f2bf(float f) {
    __bf16 b = (__bf16)f;
    unsigned short u;
    __builtin_memcpy(&u, &b, 2);
    return u;
}
__device__ __forceinline__ unsigned f2bfpk(float a, float b) {
    bfv2 v;
    v[0] = (__bf16)a;
    v[1] = (__bf16)b;
    unsigned u;
    __builtin_memcpy(&u, &v, 4);
    return u;
}
__device__ __forceinline__ float bf2f(unsigned short h) {
    return __uint_as_float(((unsigned)h) << 16);
}
__device__ __forceinline__ int fkey(float f) { int b = __float_as_int(f); return b >= 0 ? b : b ^ 0x7fffffff; }
__device__ __forceinline__ float funkey(int k) { return __int_as_float(k >= 0 ? k : k ^ 0x7fffffff); }

// ---- DPP cross-lane (VALU pipe, zero LDS) ----
template <int CTRL>
__device__ __forceinline__ float dpp_addx(float x) {
    int yi = __builtin_amdgcn_update_dpp(0, __float_as_int(x), CTRL, 0xf, 0xf, true);
    return x + __int_as_float(yi);
}
__device__ __forceinline__ float row16_sum(float x) {
    x = dpp_addx<0xB1>(x);    // quad_perm(1,0,3,2)
    x = dpp_addx<0x4E>(x);    // quad_perm(2,3,0,1)
    x = dpp_addx<0x141>(x);   // row_half_mirror
    x = dpp_addx<0x140>(x);   // row_mirror
    return x;
}

// sigma column permutation for hbuf storage (within each 64-col head):
//   store position p = (c&15)*4 + ((c>>4)&3);  inverse c = (p&3)*16 + (p>>2)
// Epilogue's per-thread cols {nt*16+l16} are CONTIGUOUS in LDS.
// wt1/wt2 k-rows permuted identically in prep_w; layer-0 k (x feats) unpermuted.

__global__ void prep_w(const float* __restrict__ W0, const float* __restrict__ rW0,
                       const float* __restrict__ W1, const float* __restrict__ W2,
                       const float* __restrict__ al0, const float* __restrict__ ar0,
                       const float* __restrict__ al1, const float* __restrict__ ar1,
                       const float* __restrict__ al2, const float* __restrict__ ar2,
                       unsigned short* __restrict__ wt0, unsigned short* __restrict__ wt1,
                       unsigned short* __restrict__ wt2) {
    if (blockIdx.x >= 64) {
        int gid = (blockIdx.x - 64) * 256 + threadIdx.x;   // [0, 5120)
        if (gid < 1024) {            // layer 0 attn tile: k = true x-features
            int la = gid >> 6, k = gid & 63;
            unsigned short o = 0;
            if (la < 8) {
                const float* a = (la < 4) ? al0 : ar0;
                int h = (la >> 1) & 1;
                float v = 0.f;
                for (int f = 0; f < 64; ++f) v += W0[k * 128 + h * 64 + f] * a[h * 64 + f];
                __bf16 hi = (__bf16)v;
                if (la & 1) o = f2bf(v - (float)hi);
                else __builtin_memcpy(&o, &hi, 2);
            }
            wt0[(256 + la) * 64 + k] = o;
        } else {                     // layers 1/2 attn tiles: k sigma-permuted
            int q = gid - 1024;
            int l = q >> 11;
            int la = (q >> 7) & 15, kp = q & 127;
            int ktrue = (kp & 64) + ((kp & 3) * 16) + ((kp & 63) >> 2);
            const float* W = l ? W2 : W1;
            unsigned short o = 0;
            if (la < 8) {
                const float* a = l ? ((la < 4) ? al2 : ar2) : ((la < 4) ? al1 : ar1);
                int h = (la >> 1) & 1;
                float v = 0.f;
                for (int f = 0; f < 64; ++f) v += W[ktrue * 128 + h * 64 + f] * a[h * 64 + f];
                __bf16 hi = (__bf16)v;
                if (la & 1) o = f2bf(v - (float)hi);
                else __builtin_memcpy(&o, &hi, 2);
            }
            (l ? wt2 : wt1)[(128 + la) * 128 + kp] = o;
        }
        return;
    }
    int i = blockIdx.x * 256 + threadIdx.x;
    if (i < 256 * 64) {              // wt0 main: k = true x-features
        int n = i >> 6, k = i & 63;
        float v = (n < 128) ? W0[k * 128 + n] : rW0[k * 128 + (n - 128)];
        wt0[i] = f2bf(v);
    }
    if (i < 128 * 128) {             // wt1/wt2 main: k sigma-permuted
        int n = i >> 7, kp = i & 127;
        int ktrue = (kp & 64) + ((kp & 3) * 16) + ((kp & 63) >> 2);
        wt1[i] = f2bf(W1[ktrue * 128 + n]);
        wt2[i] = f2bf(W2[ktrue * 128 + n]);
    }
}

// One GAT layer, fully in-block.  hbuf (sigma-ordered cols) holds
// (RESW: x@resW0, else: input h) on entry to the epilogue, this layer's y on
// exit.  NO float atomics: uniquely-owned LDS slots + fixed-order sums ->
// bit-deterministic.
// R11 = VERBATIM R6 revert (measured best: kernel 135.0us, dur 226.9us).
// Seven attempts at a clean 64-reg fit (R2/R4/R6/R7/R8/R9/R10) all spilled;
// R6's particular spill pattern (77MB, off the critical path) + 4 blocks/CU
// is the best measured trade.  Do not perturb without a full re-measure.
template <int K, bool RESW>
__device__ __forceinline__ void gat_layer(
    const float* __restrict__ xrow,             // RESW: this graph's x base
    const unsigned short* __restrict__ Wt,
    const float* __restrict__ gp, const float* __restrict__ bp,
    float* __restrict__ out, int layer, int g, int t,
    unsigned short* featT, unsigned short* hbuf, int* cnt,
    float* el_s, float* er_s, int* elmax_i,
    float* lnp, float* lnq, float* psum4, float* gbL)
{
    const int w = t >> 6, lane = t & 63, quad = lane >> 4, l16 = lane & 15;
    constexpr int KS = K / 32;
    constexpr int ATTN_ROW = RESW ? 256 : 128;  // attn tile base row in Wt
    const int mt = w & 3;
    int mrow = mt * 16 + l16;
    if (mrow >= NPG) mrow = NPG - 1;
    const floatx4 zf = {0.f, 0.f, 0.f, 0.f};

    // per-layer g|b reload, sigma-order.  Written before B1, read after B2.
    if (t < HF) {
        int p = (t & 64) + ((t & 15) * 4) + ((t >> 4) & 3);
        gbL[p] = gp[t];
        gbL[HF + p] = bp[t];
    }

    // ---- A-fragments (loaded HERE, not held across the prelude) ----
    bf16x8 afr[KS];
    if constexpr (RESW) {
        const float* hrow = xrow + (size_t)mrow * 64;
#pragma unroll
        for (int ks = 0; ks < KS; ++ks) {
            int k0 = ks * 32 + quad * 8;
            float4 p0 = *(const float4*)(hrow + k0);
            float4 p1 = *(const float4*)(hrow + k0 + 4);
            unsigned au[4] = {f2bfpk(p0.x, p0.y), f2bfpk(p0.z, p0.w),
                              f2bfpk(p1.x, p1.y), f2bfpk(p1.z, p1.w)};
            __builtin_memcpy(&afr[ks], au, 16);
        }
    } else {
#pragma unroll
        for (int ks = 0; ks < KS; ++ks)
            afr[ks] = *(const bf16x8*)&hbuf[mrow * HB + ks * 32 + quad * 8];
    }

    // ---- main GEMM via MFMA + featT/res stores ----
    if constexpr (RESW) {
        // two SEQUENTIAL passes of 4 N-tiles: peak acc = 16 AGPRs.
        // unroll 1 is load-bearing -- full unroll re-fuses to 32 AGPRs.
#pragma unroll 1
        for (int half = 0; half < 2; ++half) {
            const int nb = (w >> 2) * 8 + half * 4;
            floatx4 acc[4];
#pragma unroll
            for (int nt = 0; nt < 4; ++nt) acc[nt] = zf;
#pragma unroll
            for (int nt = 0; nt < 4; ++nt) {
                const unsigned short* wrow = Wt + (size_t)((nb + nt) * 16 + l16) * K;
#pragma unroll
                for (int ks = 0; ks < KS; ++ks) {
                    bf16x8 b = *(const bf16x8*)(wrow + ks * 32 + quad * 8);
                    acc[nt] = __builtin_amdgcn_mfma_f32_16x16x32_bf16(afr[ks], b, acc[nt], 0, 0, 0);
                }
            }
#pragma unroll
            for (int nt = 0; nt < 4; ++nt) {
                int n = (nb + nt) * 16 + l16;
                if (n < HF) {
                    uint2 pk = {f2bfpk(acc[nt][0], acc[nt][1]),
                                f2bfpk(acc[nt][2], acc[nt][3])};
                    *(uint2*)&featT[n * SP + mt * 16 + quad * 4] = pk;
                } else {
                    int c = n - HF;                       // residual -> sigma pos
                    int spos = (c & 64) + ((c & 15) * 4) + ((c >> 4) & 3);
#pragma unroll
                    for (int r = 0; r < 4; ++r) {
                        int dr = mt * 16 + quad * 4 + r;
                        if (dr < NPG) hbuf[dr * HB + spos] = f2bf(acc[nt][r]);
                    }
                }
            }
        }
    } else {
        const int ntbase = (w >> 2) * 4;
        floatx4 acc[4];
#pragma unroll
        for (int nt = 0; nt < 4; ++nt) acc[nt] = zf;
#pragma unroll
        for (int nt = 0; nt < 4; ++nt) {
            const unsigned short* wrow = Wt + (size_t)((ntbase + nt) * 16 + l16) * K;
#pragma unroll
            for (int ks = 0; ks < KS; ++ks) {
                bf16x8 b = *(const bf16x8*)(wrow + ks * 32 + quad * 8);
                acc[nt] = __builtin_amdgcn_mfma_f32_16x16x32_bf16(afr[ks], b, acc[nt], 0, 0, 0);
            }
        }
#pragma unroll
        for (int nt = 0; nt < 4; ++nt) {
            int n = (ntbase + nt) * 16 + l16;
            uint2 pk = {f2bfpk(acc[nt][0], acc[nt][1]),
                        f2bfpk(acc[nt][2], acc[nt][3])};
            *(uint2*)&featT[n * SP + mt * 16 + quad * 4] = pk;
        }
    }

    // ---- el/er via the appended attn N-tile; hi+lo merged with DPP xor1 ----
    if (w < 4) {
        floatx4 ae = zf;
        const unsigned short* wrow = Wt + (size_t)(ATTN_ROW + l16) * K;
#pragma unroll
        for (int ks = 0; ks < KS; ++ks) {
            bf16x8 b = *(const bf16x8*)(wrow + ks * 32 + quad * 8);
            ae = __builtin_amdgcn_mfma_f32_16x16x32_bf16(afr[ks], b, ae, 0, 0, 0);
        }
#pragma unroll
        for (int r = 0; r < 4; ++r) {
            float v = dpp_addx<0xB1>(ae[r]);              // hi + lo (xor1, VALU)
            if ((l16 & 1) == 0 && l16 < 8) {
                int row = mt * 16 + quad * 4 + r;
                int hd2 = (l16 >> 1) & 1;
                if (l16 < 4) {
                    el_s[hd2 * 64 + row] = v;
                    atomicMax(&elmax_i[hd2], fkey(v));    // int max: exact
                } else {
                    er_s[hd2 * 64 + row] = v;
                }
            }
        }
    }
    __syncthreads();   // B1

    // ---- exp A-frag + aggregation MFMA + epilogue ----
    const int hd = w >> 2, amt = w & 3;
    const int d = amt * 16 + l16;    // A-frag dst row

    const float erd = er_s[hd * 64 + d];
    const float md = leaky(funkey(elmax_i[hd]) + erd, 0.2f);
    const int dcl = d < NPG ? d : NPG - 1;
    const int* crow = &cnt[dcl * CNTW];

    bf16x8 ap[2];
    float rowsum = 0.f;
#pragma unroll
    for (int ks = 0; ks < 2; ++ks) {
        float4 ev0 = *(const float4*)&el_s[hd * 64 + ks * 32 + quad * 8];
        float4 ev1 = *(const float4*)&el_s[hd * 64 + ks * 32 + quad * 8 + 4];
        const float ev[8] = {ev0.x, ev0.y, ev0.z, ev0.w, ev1.x, ev1.y, ev1.z, ev1.w};
        int2 cw = *(const int2*)&crow[ks * 8 + quad * 2];   // 8 byte-counts
        unsigned au[4];
#pragma unroll
        for (int jp = 0; jp < 4; ++jp) {
            float e0 = ev[2 * jp] + erd;
            float e1 = ev[2 * jp + 1] + erd;
            e0 = fmaxf(e0, 0.2f * e0);
            e1 = fmaxf(e1, 0.2f * e1);
            float p0 = __expf(e0 - md);
            float p1 = __expf(e1 - md);
            int w32 = (jp & 2) ? cw.y : cw.x;
            int sh = (jp & 1) * 16;
            int c0 = (w32 >> sh) & 0xff;
            int c1 = (w32 >> (sh + 8)) & 0xff;
            unsigned pk = f2bfpk((float)c0 * p0, (float)c1 * p1);  // c==0 -> exact 0
            au[jp] = pk;
            rowsum += __uint_as_float(pk << 16) + __uint_as_float(pk & 0xffff0000u);
        }
        __builtin_memcpy(&ap[ks], au, 16);
    }
    rowsum += __shfl_xor(rowsum, 16, 64);
    rowsum += __shfl_xor(rowsum, 32, 64);
    const float rden = 1.f / fmaxf(rowsum, 1e-30f);

    floatx4 ag[4];
#pragma unroll
    for (int nt = 0; nt < 4; ++nt) ag[nt] = zf;
#pragma unroll
    for (int nt = 0; nt < 4; ++nt) {
        const unsigned short* fr = &featT[(hd * 64 + nt * 16 + l16) * SP];
#pragma unroll
        for (int ks = 0; ks < 2; ++ks) {
            bf16x8 b = *(const bf16x8*)(fr + ks * 32 + quad * 8);
            ag[nt] = __builtin_amdgcn_mfma_f32_16x16x32_bf16(ap[ks], b, ag[nt], 0, 0, 0);
        }
    }

    // scale + residual (sigma-packed b64 read); LN partials via DPP row-sum.
    // rden for row quad*4+r shuffled INLINE (no hoisted array -- reg diet).
    float s1[4] = {0, 0, 0, 0}, s2[4] = {0, 0, 0, 0};
#pragma unroll
    for (int r = 0; r < 4; ++r) {
        int dd = amt * 16 + quad * 4 + r;
        int dc = dd < NPG ? dd : NPG - 1;
        float rdv = __shfl(rden, quad * 4 + r, 16);
        uint2 rv = *(const uint2*)&hbuf[dc * HB + hd * 64 + l16 * 4];
#pragma unroll
        for (int nt = 0; nt < 4; ++nt) {
            unsigned hw = (nt & 1) ? ((nt & 2) ? rv.y >> 16 : rv.x >> 16)
                                   : ((nt & 2) ? rv.y & 0xffffu : rv.x & 0xffffu);
            float vv = fmaf(ag[nt][r], rdv, bf2f((unsigned short)hw));
            ag[nt][r] = vv;
            s1[r] += vv;
            s2[r] = fmaf(vv, vv, s2[r]);
        }
    }
#pragma unroll
    for (int r = 0; r < 4; ++r) {
        s1[r] = row16_sum(s1[r]);     // DPP: VALU pipe, zero LDS
        s2[r] = row16_sum(s2[r]);
    }
    if (l16 == 0) {
#pragma unroll
        for (int r = 0; r < 4; ++r) {
            int dd = amt * 16 + quad * 4 + r;   // slot [hd][dd]: single writer
            lnp[hd * 64 + dd] = s1[r];
            lnq[hd * 64 + dd] = s2[r];
        }
    }
    __syncthreads();   // B2: LN slots written; hbuf/featT reads done

    // re-arm elmax for the next layer (reads finished at B2, writes after B3)
    if (t < 2) elmax_i[t] = (int)0x80000000;

    // epilogue: scalar lnp/lnq reads per row (reg diet); g/b as one float4 pair
    float4 ga = *(const float4*)&gbL[hd * 64 + l16 * 4];
    float4 ba = *(const float4*)&gbL[HF + hd * 64 + l16 * 4];

    float part[4] = {0, 0, 0, 0};
#pragma unroll
    for (int r = 0; r < 4; ++r) {
        int dd = amt * 16 + quad * 4 + r;
        if (dd < NPG) {
            float mu = (lnp[dd] + lnp[64 + dd]) * (1.f / HF);   // head0 + head1
            float rs = rsqrtf((lnq[dd] + lnq[64 + dd]) * (1.f / HF) - mu * mu + 1e-5f);
            float y4[4];
#pragma unroll
            for (int nt = 0; nt < 4; ++nt) {
                float y = (ag[nt][r] - mu) * rs * ga[nt] + ba[nt];
                y = leaky(y, 0.1f);
                y4[nt] = y;
                part[nt] += y;
            }
            uint2 pk = {f2bfpk(y4[0], y4[1]), f2bfpk(y4[2], y4[3])};
            *(uint2*)&hbuf[dd * HB + hd * 64 + l16 * 4] = pk;   // sigma-packed
        }
    }
#pragma unroll
    for (int nt = 0; nt < 4; ++nt) {
        part[nt] += __shfl_xor(part[nt], 16, 64);
        part[nt] += __shfl_xor(part[nt], 32, 64);
    }
    if (quad == 0) {
#pragma unroll
        for (int nt = 0; nt < 4; ++nt)
            psum4[amt * HF + hd * 64 + nt * 16 + l16] = part[nt];  // TRUE col idx
    }
    __syncthreads();   // B3: y visible (next layer A-frags), psum4 complete

    if (t < FDIM) {
        float s = 0.f;
#pragma unroll
        for (int a4 = 0; a4 < 4; ++a4)                   // fixed summation order
            s += psum4[a4 * HF + t] + psum4[a4 * HF + t + FDIM];
        out[(size_t)g * (3 * FDIM) + layer * FDIM + t] = leaky(s * (1.f / (2 * NPG)), 0.1f);
    }
}

// One block per graph runs all 3 layers.  (512,8): the per-graph layer
// pipeline is inherently serial (no cross-layer overlap possible), so
// cross-block concurrency is the ONLY latency-hiding mechanism; 4 blocks/CU
// is the HW ceiling (32 waves).  This exact build measured 135.0us kernel /
// 226.9us dur (R6) -- best of 11 rounds.  Its 77MB spill is tolerated; all
// attempts to remove it (R7-R10) regressed.
__global__ __launch_bounds__(512, 8) void gat3_kernel(
    const float* __restrict__ x,
    const unsigned short* __restrict__ wt0,
    const unsigned short* __restrict__ wt1,
    const unsigned short* __restrict__ wt2,
    const float* __restrict__ g0, const float* __restrict__ b0,
    const float* __restrict__ g1, const float* __restrict__ b1,
    const float* __restrict__ g2, const float* __restrict__ b2,
    const int* __restrict__ src, const int* __restrict__ dst,
    float* __restrict__ out)
{
    __shared__ unsigned short featT[HF * SP];   // 18432 B
    __shared__ unsigned short hbuf[NPG * HB];   // 13600 B (res/h/y, sigma cols)
    __shared__ int cnt[NPG * CNTW];             // 3200 B, byte counts
    __shared__ float el_s[128], er_s[128];
    __shared__ int elmax_i[2];
    __shared__ float lnp[128], lnq[128];        // LN partials [head][row]
    __shared__ float psum4[4 * HF];             // readout partials [amt][col]
    __shared__ float gbL[2 * HF];               // current layer's [g|b], sigma

    const int g = blockIdx.x, t = threadIdx.x;
    const int nbase = g * NPG;

    // independent global loads at cycle 0
    int es = 0, ed = 0;
    if (t < EPG) { es = src[g * EPG + t] - nbase; ed = dst[g * EPG + t] - nbase; }

    // init
    for (int i = t; i < NPG * CNTW; i += 512) cnt[i] = 0;
    if (t < 2) elmax_i[t] = (int)0x80000000;
    __syncthreads();

    // edge counts (byte-packed, 4/int), once for all 3 layers.
    if (t < EPG) atomicAdd(&cnt[ed * CNTW + (es >> 2)], 1 << ((es & 3) * 8));
    if (t < NPG) atomicAdd(&cnt[t * CNTW + (t >> 2)], 1 << ((t & 3) * 8));

    const float* xrow = x + (size_t)nbase * 64;
    gat_layer<64, true>(xrow, wt0, g0, b0, out, 0, g, t,
                        featT, hbuf, cnt, el_s, er_s, elmax_i, lnp, lnq, psum4, gbL);
    gat_layer<128, false>(nullptr, wt1, g1, b1, out, 1, g, t,
                          featT, hbuf, cnt, el_s, er_s, elmax_i, lnp, lnq, psum4, gbL);
    gat_layer<128, false>(nullptr, wt2, g2, b2, out, 2, g, t,
                          featT, hbuf, cnt, el_s, er_s, elmax_i, lnp, lnq, psum4, gbL);
}

extern "C" void kernel_launch(void* const* d_in, const int* in_sizes, int n_in,
                              void* d_out, int out_size, void* d_ws, size_t ws_size,
                              hipStream_t stream) {
    const float* x   = (const float*)d_in[0];
    const float* W0  = (const float*)d_in[1];
    const float* al0 = (const float*)d_in[2];
    const float* ar0 = (const float*)d_in[3];
    const float* rW0 = (const float*)d_in[4];
    const float* g0  = (const float*)d_in[5];
    const float* b0  = (const float*)d_in[6];
    const float* W1  = (const float*)d_in[7];
    const float* al1 = (const float*)d_in[8];
    const float* ar1 = (const float*)d_in[9];
    const float* g1  = (const float*)d_in[10];
    const float* b1  = (const float*)d_in[11];
    const float* W2  = (const float*)d_in[12];
    const float* al2 = (const float*)d_in[13];
    const float* ar2 = (const float*)d_in[14];
    const float* g2  = (const float*)d_in[15];
    const float* b2  = (const float*)d_in[16];
    const int* src   = (const int*)d_in[17];
    const int* dst   = (const int*)d_in[18];
    float* out = (float*)d_out;

    unsigned short* wt0 = (unsigned short*)d_ws;            // 272 x 64
    unsigned short* wt1 = wt0 + 272 * 64;                   // 144 x 128
    unsigned short* wt2 = wt1 + 144 * 128;                  // 144 x 128

    prep_w<<<84, 256, 0, stream>>>(W0, rW0, W1, W2, al0, ar0, al1, ar1, al2, ar2,
                                   wt0, wt1, wt2);
    gat3_kernel<<<NGRAPH, 512, 0, stream>>>(
        x, wt0, wt1, wt2, g0, b0, g1, b1, g2, b2, src, dst, out);
}

// Round 12
// 182.896 us; speedup vs baseline: 1.5634x; 1.2490x over previous
//
#include <hip/hip_runtime.h>

#define NPG    50
#define HF     128
#define FDIM   64
#define NGRAPH 2048
#define EPG    400
#define SP     72     // featT row stride (bf16), 16B-aligned rows, bank-skewed
#define HB     136    // hbuf row stride (bf16), 16B-aligned rows
#define CNTW   16     // cnt row stride in ints (64 byte-counts per row)

typedef __attribute__((ext_vector_type(8))) short bf16x8;
typedef __attribute__((ext_vector_type(4))) float floatx4;
typedef __bf16 bfv2 __attribute__((ext_vector_type(2)));

__device__ __forceinline__ float leaky(float x, float s) { return x >= 0.f ? x : x * s; }

__device__ __forceinline__ unsigned short f2bf(float f) {
    __bf16 b = (__bf16)f;
    unsigned short u;
    __builtin_memcpy(&u, &b, 2);
    return u;
}
__device__ __forceinline__ unsigned f2bfpk(float a, float b) {
    bfv2 v;
    v[0] = (__bf16)a;
    v[1] = (__bf16)b;
    unsigned u;
    __builtin_memcpy(&u, &v, 4);
    return u;
}
__device__ __forceinline__ float bf2f(unsigned short h) {
    return __uint_as_float(((unsigned)h) << 16);
}
__device__ __forceinline__ int fkey(float f) { int b = __float_as_int(f); return b >= 0 ? b : b ^ 0x7fffffff; }
__device__ __forceinline__ float funkey(int k) { return __int_as_float(k >= 0 ? k : k ^ 0x7fffffff); }

// ---- async global->LDS, 16B/lane, ZERO VGPR destinations (R12) -------------
// The diagnosed root cause of 7 spill failures: global B-fragment loads hoist
// 32-64 VGPRs of load destinations.  global_load_lds has NO VGPR transit.
__device__ __forceinline__ void gld16(const void* g, void* l) {
    __builtin_amdgcn_global_load_lds(
        (const __attribute__((address_space(1))) void*)g,
        (__attribute__((address_space(3))) void*)l, 16, 0, 0);
}

// Stage a W^T matrix into LDS.  LDS layout is LINEAR (global_load_lds writes
// wave-uniform base + lane*16 -- m104); the bank-deconflict XOR swizzle is
// applied on the GLOBAL SOURCE address here and on the LDS READ address in
// wt_read (both-sides-or-neither, rule #21).  swz: byte ^= ((row&7)<<4) --
// spreads the 16 same-column rows of a wave's ds_read_b128 across 8 16B slots
// -> 2-way bank aliasing = free (m136).  XOR stays within the row for both
// row strides (112 < 128 <= KROWB).
__device__ __forceinline__ void stage_wt(const unsigned short* __restrict__ wg,
                                         unsigned short* wtbuf, int t,
                                         int totb, int krsh) {
    const int w = t >> 6, lane = t & 63;
    for (int c = w; c * 1024 < totb; c += 8) {          // wave-uniform guard
        int G = c * 1024 + lane * 16;
        int Gs = G ^ (((G >> krsh) & 7) << 4);          // pre-swizzled source
        gld16((const char*)wg + Gs, (char*)wtbuf + c * 1024);
    }
}

// Swizzled B-fragment read from the staged wtbuf.
template <int KROWB>
__device__ __forceinline__ bf16x8 wt_read(const unsigned short* wtbuf, int row, int cb) {
    int byte = (row * KROWB + cb) ^ ((row & 7) << 4);
    return *(const bf16x8*)((const char*)wtbuf + byte);
}

// ---- DPP cross-lane (VALU pipe, zero LDS) ----
template <int CTRL>
__device__ __forceinline__ float dpp_addx(float x) {
    int yi = __builtin_amdgcn_update_dpp(0, __float_as_int(x), CTRL, 0xf, 0xf, true);
    return x + __int_as_float(yi);
}
__device__ __forceinline__ float row16_sum(float x) {
    x = dpp_addx<0xB1>(x);    // quad_perm(1,0,3,2)
    x = dpp_addx<0x4E>(x);    // quad_perm(2,3,0,1)
    x = dpp_addx<0x141>(x);   // row_half_mirror
    x = dpp_addx<0x140>(x);   // row_mirror
    return x;
}

// sigma column permutation for hbuf storage (within each 64-col head):
//   store position p = (c&15)*4 + ((c>>4)&3);  inverse c = (p&3)*16 + (p>>2)
// Epilogue's per-thread cols {nt*16+l16} are CONTIGUOUS in LDS.
// wt1/wt2 k-rows permuted identically in prep_w; layer-0 k (x feats) unpermuted.

__global__ void prep_w(const float* __restrict__ W0, const float* __restrict__ rW0,
                       const float* __restrict__ W1, const float* __restrict__ W2,
                       const float* __restrict__ al0, const float* __restrict__ ar0,
                       const float* __restrict__ al1, const float* __restrict__ ar1,
                       const float* __restrict__ al2, const float* __restrict__ ar2,
                       unsigned short* __restrict__ wt0, unsigned short* __restrict__ wt1,
                       unsigned short* __restrict__ wt2) {
    if (blockIdx.x >= 64) {
        int gid = (blockIdx.x - 64) * 256 + threadIdx.x;   // [0, 5120)
        if (gid < 1024) {            // layer 0 attn tile: k = true x-features
            int la = gid >> 6, k = gid & 63;
            unsigned short o = 0;
            if (la < 8) {
                const float* a = (la < 4) ? al0 : ar0;
                int h = (la >> 1) & 1;
                float v = 0.f;
                for (int f = 0; f < 64; ++f) v += W0[k * 128 + h * 64 + f] * a[h * 64 + f];
                __bf16 hi = (__bf16)v;
                if (la & 1) o = f2bf(v - (float)hi);
                else __builtin_memcpy(&o, &hi, 2);
            }
            wt0[(256 + la) * 64 + k] = o;
        } else {                     // layers 1/2 attn tiles: k sigma-permuted
            int q = gid - 1024;
            int l = q >> 11;
            int la = (q >> 7) & 15, kp = q & 127;
            int ktrue = (kp & 64) + ((kp & 3) * 16) + ((kp & 63) >> 2);
            const float* W = l ? W2 : W1;
            unsigned short o = 0;
            if (la < 8) {
                const float* a = l ? ((la < 4) ? al2 : ar2) : ((la < 4) ? al1 : ar1);
                int h = (la >> 1) & 1;
                float v = 0.f;
                for (int f = 0; f < 64; ++f) v += W[ktrue * 128 + h * 64 + f] * a[h * 64 + f];
                __bf16 hi = (__bf16)v;
                if (la & 1) o = f2bf(v - (float)hi);
                else __builtin_memcpy(&o, &hi, 2);
            }
            (l ? wt2 : wt1)[(128 + la) * 128 + kp] = o;
        }
        return;
    }
    int i = blockIdx.x * 256 + threadIdx.x;
    if (i < 256 * 64) {              // wt0 main: k = true x-features
        int n = i >> 6, k = i & 63;
        float v = (n < 128) ? W0[k * 128 + n] : rW0[k * 128 + (n - 128)];
        wt0[i] = f2bf(v);
    }
    if (i < 128 * 128) {             // wt1/wt2 main: k sigma-permuted
        int n = i >> 7, kp = i & 127;
        int ktrue = (kp & 64) + ((kp & 3) * 16) + ((kp & 63) >> 2);
        wt1[i] = f2bf(W1[ktrue * 128 + n]);
        wt2[i] = f2bf(W2[ktrue * 128 + n]);
    }
}

// One GAT layer, fully in-block.  hbuf (sigma-ordered cols) holds
// (RESW: x@resW0, else: input h) on entry to the epilogue, this layer's y on
// exit.  NO float atomics: uniquely-owned LDS slots + fixed-order sums ->
// bit-deterministic.
// R12 = R6 structure, but ALL W^T (B-operand) reads come from the LDS-staged
// wtbuf (ds_read_b128, swizzled) instead of global -- removes both the vmem
// latency and the hoisted-load-destination register demand.  Next layer's
// weights are staged right after B1 (wtbuf is dead post-B1); the staging
// drains at B2/B3's implicit vmcnt(0) -> fully hidden under softmax/agg.
template <int K, bool RESW, bool STAGE_NEXT>
__device__ __forceinline__ void gat_layer(
    const float* __restrict__ xrow,             // RESW: this graph's x base
    const unsigned short* __restrict__ wnext,   // next layer's W^T (global)
    const float* __restrict__ gp, const float* __restrict__ bp,
    float* __restrict__ out, int layer, int g, int t,
    unsigned short* wtbuf, unsigned short* featT, unsigned short* hbuf, int* cnt,
    float* el_s, float* er_s, int* elmax_i,
    float* lnp, float* lnq, float* psum4, float* gbL)
{
    const int w = t >> 6, lane = t & 63, quad = lane >> 4, l16 = lane & 15;
    constexpr int KS = K / 32;
    constexpr int KROWB = 2 * K;                // wtbuf row stride in bytes
    constexpr int ATTN_ROW = RESW ? 256 : 128;  // attn tile base row
    const int mt = w & 3;
    int mrow = mt * 16 + l16;
    if (mrow >= NPG) mrow = NPG - 1;
    const floatx4 zf = {0.f, 0.f, 0.f, 0.f};

    // per-layer g|b reload, sigma-order.  Written before B1, read after B2.
    if (t < HF) {
        int p = (t & 64) + ((t & 15) * 4) + ((t >> 4) & 3);
        gbL[p] = gp[t];
        gbL[HF + p] = bp[t];
    }

    // ---- A-fragments (loaded HERE, not held across the prelude) ----
    bf16x8 afr[KS];
    if constexpr (RESW) {
        const float* hrow = xrow + (size_t)mrow * 64;
#pragma unroll
        for (int ks = 0; ks < KS; ++ks) {
            int k0 = ks * 32 + quad * 8;
            float4 p0 = *(const float4*)(hrow + k0);
            float4 p1 = *(const float4*)(hrow + k0 + 4);
            unsigned au[4] = {f2bfpk(p0.x, p0.y), f2bfpk(p0.z, p0.w),
                              f2bfpk(p1.x, p1.y), f2bfpk(p1.z, p1.w)};
            __builtin_memcpy(&afr[ks], au, 16);
        }
    } else {
#pragma unroll
        for (int ks = 0; ks < KS; ++ks)
            afr[ks] = *(const bf16x8*)&hbuf[mrow * HB + ks * 32 + quad * 8];
    }

    // ---- main GEMM via MFMA + featT/res stores (B from LDS wtbuf) ----
    if constexpr (RESW) {
        // two SEQUENTIAL passes of 4 N-tiles: peak acc = 16 AGPRs.
        // unroll 1 is load-bearing -- full unroll re-fuses to 32 AGPRs.
#pragma unroll 1
        for (int half = 0; half < 2; ++half) {
            const int nb = (w >> 2) * 8 + half * 4;
            floatx4 acc[4];
#pragma unroll
            for (int nt = 0; nt < 4; ++nt) acc[nt] = zf;
#pragma unroll
            for (int nt = 0; nt < 4; ++nt) {
#pragma unroll
                for (int ks = 0; ks < KS; ++ks) {
                    bf16x8 b = wt_read<KROWB>(wtbuf, (nb + nt) * 16 + l16, ks * 64 + quad * 16);
                    acc[nt] = __builtin_amdgcn_mfma_f32_16x16x32_bf16(afr[ks], b, acc[nt], 0, 0, 0);
                }
            }
#pragma unroll
            for (int nt = 0; nt < 4; ++nt) {
                int n = (nb + nt) * 16 + l16;
                if (n < HF) {
                    uint2 pk = {f2bfpk(acc[nt][0], acc[nt][1]),
                                f2bfpk(acc[nt][2], acc[nt][3])};
                    *(uint2*)&featT[n * SP + mt * 16 + quad * 4] = pk;
                } else {
                    int c = n - HF;                       // residual -> sigma pos
                    int spos = (c & 64) + ((c & 15) * 4) + ((c >> 4) & 3);
#pragma unroll
                    for (int r = 0; r < 4; ++r) {
                        int dr = mt * 16 + quad * 4 + r;
                        if (dr < NPG) hbuf[dr * HB + spos] = f2bf(acc[nt][r]);
                    }
                }
            }
        }
    } else {
        const int ntbase = (w >> 2) * 4;
        floatx4 acc[4];
#pragma unroll
        for (int nt = 0; nt < 4; ++nt) acc[nt] = zf;
#pragma unroll
        for (int nt = 0; nt < 4; ++nt) {
#pragma unroll
            for (int ks = 0; ks < KS; ++ks) {
                bf16x8 b = wt_read<KROWB>(wtbuf, (ntbase + nt) * 16 + l16, ks * 64 + quad * 16);
                acc[nt] = __builtin_amdgcn_mfma_f32_16x16x32_bf16(afr[ks], b, acc[nt], 0, 0, 0);
            }
        }
#pragma unroll
        for (int nt = 0; nt < 4; ++nt) {
            int n = (ntbase + nt) * 16 + l16;
            uint2 pk = {f2bfpk(acc[nt][0], acc[nt][1]),
                        f2bfpk(acc[nt][2], acc[nt][3])};
            *(uint2*)&featT[n * SP + mt * 16 + quad * 4] = pk;
        }
    }

    // ---- el/er via the appended attn N-tile; hi+lo merged with DPP xor1 ----
    if (w < 4) {
        floatx4 ae = zf;
#pragma unroll
        for (int ks = 0; ks < KS; ++ks) {
            bf16x8 b = wt_read<KROWB>(wtbuf, ATTN_ROW + l16, ks * 64 + quad * 16);
            ae = __builtin_amdgcn_mfma_f32_16x16x32_bf16(afr[ks], b, ae, 0, 0, 0);
        }
#pragma unroll
        for (int r = 0; r < 4; ++r) {
            float v = dpp_addx<0xB1>(ae[r]);              // hi + lo (xor1, VALU)
            if ((l16 & 1) == 0 && l16 < 8) {
                int row = mt * 16 + quad * 4 + r;
                int hd2 = (l16 >> 1) & 1;
                if (l16 < 4) {
                    el_s[hd2 * 64 + row] = v;
                    atomicMax(&elmax_i[hd2], fkey(v));    // int max: exact
                } else {
                    er_s[hd2 * 64 + row] = v;
                }
            }
        }
    }
    __syncthreads();   // B1: wtbuf reads done -> safe to overwrite

    // stage NEXT layer's weights now; latency hides under softmax/agg and
    // drains at B2/B3's implicit vmcnt(0).  wt1/wt2 are always K=128.
    if constexpr (STAGE_NEXT) stage_wt(wnext, wtbuf, t, 144 * 256, 8);

    // ---- exp A-frag + aggregation MFMA + epilogue ----
    const int hd = w >> 2, amt = w & 3;
    const int d = amt * 16 + l16;    // A-frag dst row

    const float erd = er_s[hd * 64 + d];
    const float md = leaky(funkey(elmax_i[hd]) + erd, 0.2f);
    const int dcl = d < NPG ? d : NPG - 1;
    const int* crow = &cnt[dcl * CNTW];

    bf16x8 ap[2];
    float rowsum = 0.f;
#pragma unroll
    for (int ks = 0; ks < 2; ++ks) {
        float4 ev0 = *(const float4*)&el_s[hd * 64 + ks * 32 + quad * 8];
        float4 ev1 = *(const float4*)&el_s[hd * 64 + ks * 32 + quad * 8 + 4];
        const float ev[8] = {ev0.x, ev0.y, ev0.z, ev0.w, ev1.x, ev1.y, ev1.z, ev1.w};
        int2 cw = *(const int2*)&crow[ks * 8 + quad * 2];   // 8 byte-counts
        unsigned au[4];
#pragma unroll
        for (int jp = 0; jp < 4; ++jp) {
            float e0 = ev[2 * jp] + erd;
            float e1 = ev[2 * jp + 1] + erd;
            e0 = fmaxf(e0, 0.2f * e0);
            e1 = fmaxf(e1, 0.2f * e1);
            float p0 = __expf(e0 - md);
            float p1 = __expf(e1 - md);
            int w32 = (jp & 2) ? cw.y : cw.x;
            int sh = (jp & 1) * 16;
            int c0 = (w32 >> sh) & 0xff;
            int c1 = (w32 >> (sh + 8)) & 0xff;
            unsigned pk = f2bfpk((float)c0 * p0, (float)c1 * p1);  // c==0 -> exact 0
            au[jp] = pk;
            rowsum += __uint_as_float(pk << 16) + __uint_as_float(pk & 0xffff0000u);
        }
        __builtin_memcpy(&ap[ks], au, 16);
    }
    rowsum += __shfl_xor(rowsum, 16, 64);
    rowsum += __shfl_xor(rowsum, 32, 64);
    const float rden = 1.f / fmaxf(rowsum, 1e-30f);

    floatx4 ag[4];
#pragma unroll
    for (int nt = 0; nt < 4; ++nt) ag[nt] = zf;
#pragma unroll
    for (int nt = 0; nt < 4; ++nt) {
        const unsigned short* fr = &featT[(hd * 64 + nt * 16 + l16) * SP];
#pragma unroll
        for (int ks = 0; ks < 2; ++ks) {
            bf16x8 b = *(const bf16x8*)(fr + ks * 32 + quad * 8);
            ag[nt] = __builtin_amdgcn_mfma_f32_16x16x32_bf16(ap[ks], b, ag[nt], 0, 0, 0);
        }
    }

    // scale + residual (sigma-packed b64 read); LN partials via DPP row-sum.
    // rden for row quad*4+r shuffled INLINE (no hoisted array).
    float s1[4] = {0, 0, 0, 0}, s2[4] = {0, 0, 0, 0};
#pragma unroll
    for (int r = 0; r < 4; ++r) {
        int dd = amt * 16 + quad * 4 + r;
        int dc = dd < NPG ? dd : NPG - 1;
        float rdv = __shfl(rden, quad * 4 + r, 16);
        uint2 rv = *(const uint2*)&hbuf[dc * HB + hd * 64 + l16 * 4];
#pragma unroll
        for (int nt = 0; nt < 4; ++nt) {
            unsigned hw = (nt & 1) ? ((nt & 2) ? rv.y >> 16 : rv.x >> 16)
                                   : ((nt & 2) ? rv.y & 0xffffu : rv.x & 0xffffu);
            float vv = fmaf(ag[nt][r], rdv, bf2f((unsigned short)hw));
            ag[nt][r] = vv;
            s1[r] += vv;
            s2[r] = fmaf(vv, vv, s2[r]);
        }
    }
#pragma unroll
    for (int r = 0; r < 4; ++r) {
        s1[r] = row16_sum(s1[r]);     // DPP: VALU pipe, zero LDS
        s2[r] = row16_sum(s2[r]);
    }
    if (l16 == 0) {
#pragma unroll
        for (int r = 0; r < 4; ++r) {
            int dd = amt * 16 + quad * 4 + r;   // slot [hd][dd]: single writer
            lnp[hd * 64 + dd] = s1[r];
            lnq[hd * 64 + dd] = s2[r];
        }
    }
    __syncthreads();   // B2: LN slots written; hbuf/featT reads done

    // re-arm elmax for the next layer (reads finished at B2, writes after B3)
    if (t < 2) elmax_i[t] = (int)0x80000000;

    // epilogue: scalar lnp/lnq reads per row; g/b as one float4 pair
    float4 ga = *(const float4*)&gbL[hd * 64 + l16 * 4];
    float4 ba = *(const float4*)&gbL[HF + hd * 64 + l16 * 4];

    float part[4] = {0, 0, 0, 0};
#pragma unroll
    for (int r = 0; r < 4; ++r) {
        int dd = amt * 16 + quad * 4 + r;
        if (dd < NPG) {
            float mu = (lnp[dd] + lnp[64 + dd]) * (1.f / HF);   // head0 + head1
            float rs = rsqrtf((lnq[dd] + lnq[64 + dd]) * (1.f / HF) - mu * mu + 1e-5f);
            float y4[4];
#pragma unroll
            for (int nt = 0; nt < 4; ++nt) {
                float y = (ag[nt][r] - mu) * rs * ga[nt] + ba[nt];
                y = leaky(y, 0.1f);
                y4[nt] = y;
                part[nt] += y;
            }
            uint2 pk = {f2bfpk(y4[0], y4[1]), f2bfpk(y4[2], y4[3])};
            *(uint2*)&hbuf[dd * HB + hd * 64 + l16 * 4] = pk;   // sigma-packed
        }
    }
#pragma unroll
    for (int nt = 0; nt < 4; ++nt) {
        part[nt] += __shfl_xor(part[nt], 16, 64);
        part[nt] += __shfl_xor(part[nt], 32, 64);
    }
    if (quad == 0) {
#pragma unroll
        for (int nt = 0; nt < 4; ++nt)
            psum4[amt * HF + hd * 64 + nt * 16 + l16] = part[nt];  // TRUE col idx
    }
    __syncthreads();   // B3: y visible (next layer A-frags), psum4 complete

    if (t < FDIM) {
        float s = 0.f;
#pragma unroll
        for (int a4 = 0; a4 < 4; ++a4)                   // fixed summation order
            s += psum4[a4 * HF + t] + psum4[a4 * HF + t + FDIM];
        out[(size_t)g * (3 * FDIM) + layer * FDIM + t] = leaky(s * (1.f / (2 * NPG)), 0.1f);
    }
}

// One block per graph runs all 3 layers.  (512,4): 2 blocks/CU (LDS 77.3 KB
// each) -> 128-reg budget per wave, which the kernel's natural ~70-85 demand
// fits CLEAN (the 64-reg budget failed 7 times).  B-operands come from the
// LDS-staged wtbuf via global_load_lds (zero VGPR transit).  Trade under
// test: 2 clean blocks + LDS-B (this) vs 4 spilled blocks + global-B (R6,
// 135us).  Tripwire: WRITE_SIZE must be ~1.5-5 MB; kernel >150us => revert.
__global__ __launch_bounds__(512, 4) void gat3_kernel(
    const float* __restrict__ x,
    const unsigned short* __restrict__ wt0,
    const unsigned short* __restrict__ wt1,
    const unsigned short* __restrict__ wt2,
    const float* __restrict__ g0, const float* __restrict__ b0,
    const float* __restrict__ g1, const float* __restrict__ b1,
    const float* __restrict__ g2, const float* __restrict__ b2,
    const int* __restrict__ src, const int* __restrict__ dst,
    float* __restrict__ out)
{
    __shared__ unsigned short wtbuf[144 * 128];  // 36864 B: current layer W^T
    __shared__ unsigned short featT[HF * SP];    // 18432 B
    __shared__ unsigned short hbuf[NPG * HB];    // 13600 B (res/h/y, sigma cols)
    __shared__ int cnt[NPG * CNTW];              // 3200 B, byte counts
    __shared__ float el_s[128], er_s[128];
    __shared__ int elmax_i[2];
    __shared__ float lnp[128], lnq[128];         // LN partials [head][row]
    __shared__ float psum4[4 * HF];              // readout partials [amt][col]
    __shared__ float gbL[2 * HF];                // current layer's [g|b], sigma

    const int g = blockIdx.x, t = threadIdx.x;
    const int nbase = g * NPG;

    // stage L0 weights FIRST (async, no VGPR transit; drains at the barrier)
    stage_wt(wt0, wtbuf, t, 272 * 128, 7);       // 34816 B, row stride 128 B

    // independent global loads at cycle 0
    int es = 0, ed = 0;
    if (t < EPG) { es = src[g * EPG + t] - nbase; ed = dst[g * EPG + t] - nbase; }

    // init
    for (int i = t; i < NPG * CNTW; i += 512) cnt[i] = 0;
    if (t < 2) elmax_i[t] = (int)0x80000000;
    __syncthreads();   // B0: wtbuf(L0) staged (vmcnt(0) drain), cnt zeroed

    // edge counts (byte-packed, 4/int), once for all 3 layers.
    if (t < EPG) atomicAdd(&cnt[ed * CNTW + (es >> 2)], 1 << ((es & 3) * 8));
    if (t < NPG) atomicAdd(&cnt[t * CNTW + (t >> 2)], 1 << ((t & 3) * 8));

    const float* xrow = x + (size_t)nbase * 64;
    gat_layer<64, true, true>(xrow, wt1, g0, b0, out, 0, g, t,
                              wtbuf, featT, hbuf, cnt, el_s, er_s, elmax_i, lnp, lnq, psum4, gbL);
    gat_layer<128, false, true>(nullptr, wt2, g1, b1, out, 1, g, t,
                                wtbuf, featT, hbuf, cnt, el_s, er_s, elmax_i, lnp, lnq, psum4, gbL);
    gat_layer<128, false, false>(nullptr, nullptr, g2, b2, out, 2, g, t,
                                 wtbuf, featT, hbuf, cnt, el_s, er_s, elmax_i, lnp, lnq, psum4, gbL);
}

extern "C" void kernel_launch(void* const* d_in, const int* in_sizes, int n_in,
                              void* d_out, int out_size, void* d_ws, size_t ws_size,
                              hipStream_t stream) {
    const float* x   = (const float*)d_in[0];
    const float* W0  = (const float*)d_in[1];
    const float* al0 = (const float*)d_in[2];
    const float* ar0 = (const float*)d_in[3];
    const float* rW0 = (const float*)d_in[4];
    const float* g0  = (const float*)d_in[5];
    const float* b0  = (const float*)d_in[6];
    const float* W1  = (const float*)d_in[7];
    const float* al1 = (const float*)d_in[8];
    const float* ar1 = (const float*)d_in[9];
    const float* g1  = (const float*)d_in[10];
    const float* b1  = (const float*)d_in[11];
    const float* W2  = (const float*)d_in[12];
    const float* al2 = (const float*)d_in[13];
    const float* ar2 = (const float*)d_in[14];
    const float* g2  = (const float*)d_in[15];
    const float* b2  = (const float*)d_in[16];
    const int* src   = (const int*)d_in[17];
    const int* dst   = (const int*)d_in[18];
    float* out = (float*)d_out;

    unsigned short* wt0 = (unsigned short*)d_ws;            // 272 x 64
    unsigned short* wt1 = wt0 + 272 * 64;                   // 144 x 128
    unsigned short* wt2 = wt1 + 144 * 128;                  // 144 x 128

    prep_w<<<84, 256, 0, stream>>>(W0, rW0, W1, W2, al0, ar0, al1, ar1, al2, ar2,
                                   wt0, wt1, wt2);
    gat3_kernel<<<NGRAPH, 512, 0, stream>>>(
        x, wt0, wt1, wt2, g0, b0, g1, b1, g2, b2, src, dst, out);
}